// Round 7
// baseline (119.959 us; speedup 1.0000x reference)
//
#include <hip/hip_runtime.h>

#define OUT_UNITS 128

// ---------------- Kernel 1: CSR row pointers from sorted COO rows ------------
__global__ void build_row_starts(const int* __restrict__ rows,
                                 int* __restrict__ row_start,
                                 int nnz, int n_rows) {
    int k = blockIdx.x * blockDim.x + threadIdx.x;
    if (k >= nnz) return;
    int cur = rows[k];
    if (k == 0) {
        for (int r = 0; r <= cur; ++r) row_start[r] = 0;
    } else {
        int prev = rows[k - 1];
        for (int r = prev + 1; r <= cur; ++r) row_start[r] = k;
    }
    if (k == nnz - 1) {
        for (int r = cur + 1; r <= n_rows; ++r) row_start[r] = nnz;
    }
}

// ---------------- Kernel 2: 4 waves/block, one row per wave ------------------
// No readlane (convergent -> pinned schedule in rounds 5/6, MLP=1).
// r is forced wave-uniform via readfirstlane, so start/end/gbase are SGPRs
// and cols/vals become s_load_dwordx16 (scalar pipe). Gather addresses are
// SGPR row base + constant lane voffset. The 16-gather issue loop has no
// convergent ops and no inter-load deps -> scheduler can keep all 16 in
// flight. Groups padded to 16 with scalar-predicated v=0; final group
// clamped to avoid OOB.
__global__ __launch_bounds__(256, 4)
void spmm_row_wave(const float* __restrict__ vals,
                   const float* __restrict__ w,
                   const int* __restrict__ cols,
                   const int* __restrict__ row_start,
                   float* __restrict__ out,
                   int nnz, int n_rows) {
    const int wave = __builtin_amdgcn_readfirstlane((int)(threadIdx.x >> 6));
    const int r    = blockIdx.x * 4 + wave;
    if (r >= n_rows) return;

    const int start = row_start[r];      // uniform -> s_load
    const int end   = row_start[r + 1];  // uniform -> s_load
    const int lane  = threadIdx.x & 63;
    const char* __restrict__ wb = (const char*)w;
    const int loff  = lane << 3;         // lane*8 bytes: 64 lanes = 512B row

    float2 a0 = make_float2(0.f, 0.f);
    float2 a1 = make_float2(0.f, 0.f);
    float2 a2 = make_float2(0.f, 0.f);
    float2 a3 = make_float2(0.f, 0.f);

    for (int gb = start; gb < end; gb += 16) {
        const int gbase = min(gb, nnz - 16);  // clamp: never read past cols/vals

        // ---- scalar phase: 16 cols + 16 vals, uniform addrs -> SMEM ----
        int   c[16];
        float v[16];
#pragma unroll
        for (int j = 0; j < 16; ++j) {
            const int idx = gbase + j;
            c[j] = cols[idx];
            float vv = vals[idx];
            v[j] = (idx >= gb && idx < end) ? vv : 0.f;  // scalar cselect
        }

        // ---- issue phase: 16 independent saddr-form dwordx2 gathers ----
        float2 wbuf[16];
#pragma unroll
        for (int j = 0; j < 16; ++j) {
            wbuf[j] = *(const float2*)(wb + (((size_t)(unsigned)c[j]) << 9) + loff);
        }

        // ---- consume phase: 4 independent fma chains, issue order ----
#pragma unroll
        for (int j = 0; j < 16; j += 4) {
            a0.x = fmaf(v[j],     wbuf[j].x,     a0.x);
            a0.y = fmaf(v[j],     wbuf[j].y,     a0.y);
            a1.x = fmaf(v[j + 1], wbuf[j + 1].x, a1.x);
            a1.y = fmaf(v[j + 1], wbuf[j + 1].y, a1.y);
            a2.x = fmaf(v[j + 2], wbuf[j + 2].x, a2.x);
            a2.y = fmaf(v[j + 2], wbuf[j + 2].y, a2.y);
            a3.x = fmaf(v[j + 3], wbuf[j + 3].x, a3.x);
            a3.y = fmaf(v[j + 3], wbuf[j + 3].y, a3.y);
        }
    }

    float2 acc = make_float2((a0.x + a1.x) + (a2.x + a3.x),
                             (a0.y + a1.y) + (a2.y + a3.y));
    ((float2*)(out + (size_t)r * OUT_UNITS))[lane] = acc;
}

extern "C" void kernel_launch(void* const* d_in, const int* in_sizes, int n_in,
                              void* d_out, int out_size, void* d_ws, size_t ws_size,
                              hipStream_t stream) {
    const float* vals = (const float*)d_in[0];
    const float* w    = (const float*)d_in[1];
    const int*   rows = (const int*)d_in[2];
    const int*   cols = (const int*)d_in[3];
    float* out = (float*)d_out;

    const int nnz    = in_sizes[0];
    const int n_rows = out_size / OUT_UNITS;  // 16384

    int* row_start = (int*)d_ws;  // (n_rows + 1) ints

    build_row_starts<<<(nnz + 255) / 256, 256, 0, stream>>>(rows, row_start, nnz, n_rows);
    spmm_row_wave<<<(n_rows + 3) / 4, 256, 0, stream>>>(vals, w, cols, row_start, out, nnz, n_rows);
}

// Round 8
// 98.830 us; speedup vs baseline: 1.2138x; 1.2138x over previous
//
#include <hip/hip_runtime.h>

#define OUT_UNITS 128

// ---------------- Kernel 1: CSR row pointers from sorted COO rows ------------
__global__ void build_row_starts(const int* __restrict__ rows,
                                 int* __restrict__ row_start,
                                 int nnz, int n_rows) {
    int k = blockIdx.x * blockDim.x + threadIdx.x;
    if (k >= nnz) return;
    int cur = rows[k];
    if (k == 0) {
        for (int r = 0; r <= cur; ++r) row_start[r] = 0;
    } else {
        int prev = rows[k - 1];
        for (int r = prev + 1; r <= cur; ++r) row_start[r] = k;
    }
    if (k == nnz - 1) {
        for (int r = cur + 1; r <= n_rows; ++r) row_start[r] = nnz;
    }
}

// ---------------- Kernel 2: 4 waves/block, one row per wave ------------------
// cols/vals broadcast via per-wave LDS region (ds_read_b64, 2-way broadcast,
// NOT convergent -> scheduler may reorder/cluster, unlike readlane which
// pinned MLP to 1 in rounds 4-7). Half-wave split: lanes 0-31 handle nnz 2t,
// lanes 32-63 handle nnz 2t+1, float4 gather -> one 1KB instr per 2 nnz.
// Manual 4x unroll: 4 ds_reads, 4 independent gathers, 16 fma. No barriers:
// each wave touches only its own LDS region (program-ordered within a wave).
__global__ __launch_bounds__(256)
void spmm_row_wave(const float* __restrict__ vals,
                   const float* __restrict__ w,
                   const int* __restrict__ cols,
                   const int* __restrict__ row_start,
                   float* __restrict__ out,
                   int n_rows) {
    __shared__ int2 cvbuf[4][64];

    const int wave = __builtin_amdgcn_readfirstlane((int)(threadIdx.x >> 6));
    const int lane = threadIdx.x & 63;
    const int r    = blockIdx.x * 4 + wave;
    if (r >= n_rows) return;

    const int start = row_start[r];
    const int end   = row_start[r + 1];
    const int half  = lane >> 5;   // which nnz of the pair
    const int sub   = lane & 31;   // 32 lanes x float4 = 128 floats = one w row
    const float4* __restrict__ w4 = (const float4*)w;  // row c: w4[c*32 + sub]
    int2* cv = cvbuf[wave];

    float4 acc = make_float4(0.f, 0.f, 0.f, 0.f);

    for (int base = start; base < end; base += 64) {
        const int navail = min(64, end - base);
        // stage (c, v) pairs; pad lanes get (valid col, v=0)
        const int idx = base + min(lane, navail - 1);
        int   c_l = cols[idx];
        float v_l = (lane < navail) ? vals[idx] : 0.f;
        cv[lane] = make_int2(c_l, __float_as_int(v_l));

        const int npair  = (navail + 1) >> 1;
        const int npair4 = (npair + 3) & ~3;   // <=32; pad pairs have v=0

        for (int t = 0; t < npair4; t += 4) {
            // ---- 4 broadcast LDS reads (independent) ----
            int2 p0 = cv[2 * t + 0 + half];
            int2 p1 = cv[2 * t + 2 + half];
            int2 p2 = cv[2 * t + 4 + half];
            int2 p3 = cv[2 * t + 6 + half];
            // ---- 4 independent 1KB gathers ----
            float4 w0 = w4[((size_t)(unsigned)p0.x << 5) + sub];
            float4 w1 = w4[((size_t)(unsigned)p1.x << 5) + sub];
            float4 w2 = w4[((size_t)(unsigned)p2.x << 5) + sub];
            float4 w3 = w4[((size_t)(unsigned)p3.x << 5) + sub];
            // ---- consume in issue order; acc.{x,y,z,w} are 4 indep chains ----
            float v0 = __int_as_float(p0.y);
            float v1 = __int_as_float(p1.y);
            float v2 = __int_as_float(p2.y);
            float v3 = __int_as_float(p3.y);
            acc.x = fmaf(v0, w0.x, acc.x); acc.y = fmaf(v0, w0.y, acc.y);
            acc.z = fmaf(v0, w0.z, acc.z); acc.w = fmaf(v0, w0.w, acc.w);
            acc.x = fmaf(v1, w1.x, acc.x); acc.y = fmaf(v1, w1.y, acc.y);
            acc.z = fmaf(v1, w1.z, acc.z); acc.w = fmaf(v1, w1.w, acc.w);
            acc.x = fmaf(v2, w2.x, acc.x); acc.y = fmaf(v2, w2.y, acc.y);
            acc.z = fmaf(v2, w2.z, acc.z); acc.w = fmaf(v2, w2.w, acc.w);
            acc.x = fmaf(v3, w3.x, acc.x); acc.y = fmaf(v3, w3.y, acc.y);
            acc.z = fmaf(v3, w3.z, acc.z); acc.w = fmaf(v3, w3.w, acc.w);
        }
    }

    // combine the two halves (disjoint nnz subsets)
    acc.x += __shfl_xor(acc.x, 32);
    acc.y += __shfl_xor(acc.y, 32);
    acc.z += __shfl_xor(acc.z, 32);
    acc.w += __shfl_xor(acc.w, 32);

    if (half == 0) {
        ((float4*)(out + (size_t)r * OUT_UNITS))[sub] = acc;
    }
}

extern "C" void kernel_launch(void* const* d_in, const int* in_sizes, int n_in,
                              void* d_out, int out_size, void* d_ws, size_t ws_size,
                              hipStream_t stream) {
    const float* vals = (const float*)d_in[0];
    const float* w    = (const float*)d_in[1];
    const int*   rows = (const int*)d_in[2];
    const int*   cols = (const int*)d_in[3];
    float* out = (float*)d_out;

    const int nnz    = in_sizes[0];
    const int n_rows = out_size / OUT_UNITS;  // 16384

    int* row_start = (int*)d_ws;  // (n_rows + 1) ints

    build_row_starts<<<(nnz + 255) / 256, 256, 0, stream>>>(rows, row_start, nnz, n_rows);
    spmm_row_wave<<<(n_rows + 3) / 4, 256, 0, stream>>>(vals, w, cols, row_start, out, n_rows);
}

// Round 9
// 98.512 us; speedup vs baseline: 1.2177x; 1.0032x over previous
//
#include <hip/hip_runtime.h>

#define OUT_UNITS 128

// ---------------- Kernel 1: CSR row pointers from sorted COO rows ------------
__global__ void build_row_starts(const int* __restrict__ rows,
                                 int* __restrict__ row_start,
                                 int nnz, int n_rows) {
    int k = blockIdx.x * blockDim.x + threadIdx.x;
    if (k >= nnz) return;
    int cur = rows[k];
    if (k == 0) {
        for (int r = 0; r <= cur; ++r) row_start[r] = 0;
    } else {
        int prev = rows[k - 1];
        for (int r = prev + 1; r <= cur; ++r) row_start[r] = k;
    }
    if (k == nnz - 1) {
        for (int r = cur + 1; r <= n_rows; ++r) row_start[r] = nnz;
    }
}

// ---------------- Kernel 2: 4 waves/block, one row per wave ------------------
// Round 8 structure (LDS broadcast of (c,v), half-wave float4 gathers: one
// 1KB instr per 2 nnz) + explicit 2-stage software pipeline: issue stage
// B's ds_reads+gathers BEFORE consuming stage A, so 8 gathers (8 KB/wave)
// stay in flight and the consume waits on vmcnt(4), never a full drain.
// All 64 LDS entries are written every chunk (pads get v=0), so pipelined
// reads of padded pairs are safe.
__global__ __launch_bounds__(256, 4)
void spmm_row_wave(const float* __restrict__ vals,
                   const float* __restrict__ w,
                   const int* __restrict__ cols,
                   const int* __restrict__ row_start,
                   float* __restrict__ out,
                   int n_rows) {
    __shared__ int2 cvbuf[4][64];

    const int wave = __builtin_amdgcn_readfirstlane((int)(threadIdx.x >> 6));
    const int lane = threadIdx.x & 63;
    const int r    = blockIdx.x * 4 + wave;
    if (r >= n_rows) return;

    const int start = row_start[r];
    const int end   = row_start[r + 1];
    const int half  = lane >> 5;   // which nnz of the pair
    const int sub   = lane & 31;   // 32 lanes x float4 = 128 floats = one w row
    const float4* __restrict__ w4 = (const float4*)w;  // row c: w4[c*32 + sub]
    int2* cv = cvbuf[wave];

    float4 acc0 = make_float4(0.f, 0.f, 0.f, 0.f);
    float4 acc1 = make_float4(0.f, 0.f, 0.f, 0.f);

    for (int base = start; base < end; base += 64) {
        const int navail = min(64, end - base);
        // stage (c, v): pad lanes get (valid col, v=0)
        const int idx = base + min(lane, navail - 1);
        int   c_l = cols[idx];
        float v_l = (lane < navail) ? vals[idx] : 0.f;
        cv[lane] = make_int2(c_l, __float_as_int(v_l));

        const int npair  = (navail + 1) >> 1;
        const int npair4 = (npair + 3) & ~3;   // <= 32

        // ---- prologue: stage A = pairs [0,4) ----
        int2   pA[4];
        float4 wA[4];
#pragma unroll
        for (int j = 0; j < 4; ++j) pA[j] = cv[2 * j + half];
#pragma unroll
        for (int j = 0; j < 4; ++j)
            wA[j] = w4[((size_t)(unsigned)pA[j].x << 5) + sub];

        for (int t = 4; t < npair4; t += 4) {
            // ---- issue stage B before consuming A ----
            int2   pB[4];
            float4 wB[4];
#pragma unroll
            for (int j = 0; j < 4; ++j) pB[j] = cv[2 * (t + j) + half];
#pragma unroll
            for (int j = 0; j < 4; ++j)
                wB[j] = w4[((size_t)(unsigned)pB[j].x << 5) + sub];
            // ---- consume stage A (waits vmcnt(4): B stays in flight) ----
#pragma unroll
            for (int j = 0; j < 4; ++j) {
                float v = __int_as_float(pA[j].y);
                float4& wv = wA[j];
                float4& a  = (j & 1) ? acc1 : acc0;
                a.x = fmaf(v, wv.x, a.x); a.y = fmaf(v, wv.y, a.y);
                a.z = fmaf(v, wv.z, a.z); a.w = fmaf(v, wv.w, a.w);
            }
            // ---- rotate B -> A ----
#pragma unroll
            for (int j = 0; j < 4; ++j) { pA[j] = pB[j]; wA[j] = wB[j]; }
        }

        // ---- epilogue: consume final stage ----
#pragma unroll
        for (int j = 0; j < 4; ++j) {
            float v = __int_as_float(pA[j].y);
            float4& wv = wA[j];
            float4& a  = (j & 1) ? acc1 : acc0;
            a.x = fmaf(v, wv.x, a.x); a.y = fmaf(v, wv.y, a.y);
            a.z = fmaf(v, wv.z, a.z); a.w = fmaf(v, wv.w, a.w);
        }
    }

    float4 acc = make_float4(acc0.x + acc1.x, acc0.y + acc1.y,
                             acc0.z + acc1.z, acc0.w + acc1.w);

    // combine the two halves (disjoint nnz subsets)
    acc.x += __shfl_xor(acc.x, 32);
    acc.y += __shfl_xor(acc.y, 32);
    acc.z += __shfl_xor(acc.z, 32);
    acc.w += __shfl_xor(acc.w, 32);

    if (half == 0) {
        ((float4*)(out + (size_t)r * OUT_UNITS))[sub] = acc;
    }
}

extern "C" void kernel_launch(void* const* d_in, const int* in_sizes, int n_in,
                              void* d_out, int out_size, void* d_ws, size_t ws_size,
                              hipStream_t stream) {
    const float* vals = (const float*)d_in[0];
    const float* w    = (const float*)d_in[1];
    const int*   rows = (const int*)d_in[2];
    const int*   cols = (const int*)d_in[3];
    float* out = (float*)d_out;

    const int nnz    = in_sizes[0];
    const int n_rows = out_size / OUT_UNITS;  // 16384

    int* row_start = (int*)d_ws;  // (n_rows + 1) ints

    build_row_starts<<<(nnz + 255) / 256, 256, 0, stream>>>(rows, row_start, nnz, n_rows);
    spmm_row_wave<<<(n_rows + 3) / 4, 256, 0, stream>>>(vals, w, cols, row_start, out, n_rows);
}

// Round 10
// 89.695 us; speedup vs baseline: 1.3374x; 1.0983x over previous
//
#include <hip/hip_runtime.h>
#include <hip/hip_fp16.h>

#define OUT_UNITS 128

// ---------------- Kernel 0: w fp32 -> fp16 into workspace --------------------
__global__ void convert_w(const float4* __restrict__ w4,
                          uint2* __restrict__ wh, int n4) {
    int i = blockIdx.x * blockDim.x + threadIdx.x;
    if (i >= n4) return;
    float4 f = w4[i];
    __half2 h01 = __floats2half2_rn(f.x, f.y);
    __half2 h23 = __floats2half2_rn(f.z, f.w);
    wh[i] = make_uint2(*(unsigned*)&h01, *(unsigned*)&h23);
}

// ---------------- Kernel 1: CSR row pointers from sorted COO rows ------------
__global__ void build_row_starts(const int* __restrict__ rows,
                                 int* __restrict__ row_start,
                                 int nnz, int n_rows) {
    int k = blockIdx.x * blockDim.x + threadIdx.x;
    if (k >= nnz) return;
    int cur = rows[k];
    if (k == 0) {
        for (int r = 0; r <= cur; ++r) row_start[r] = 0;
    } else {
        int prev = rows[k - 1];
        for (int r = prev + 1; r <= cur; ++r) row_start[r] = k;
    }
    if (k == nnz - 1) {
        for (int r = cur + 1; r <= n_rows; ++r) row_start[r] = nnz;
    }
}

// ---------------- Kernel 2: 4 waves/block, one row per wave ------------------
// fp16 w: one row = 128 halves = 256 B. Quarter-wave split: 16 lanes x 16 B
// (dwordx4, 8 halves/lane) cover one row -> one instruction serves 4 nnz
// (2x fewer VMEM instrs and bytes than round 8's fp32 float4 scheme).
// (c,v) broadcast via per-wave LDS (non-convergent ds_read, the round-8 win).
// Each lane accumulates 8 output cols fp32; shfl_xor(16,32) folds quarters.
__global__ __launch_bounds__(256, 4)
void spmm_row_wave(const float* __restrict__ vals,
                   const __half* __restrict__ wh,
                   const int* __restrict__ cols,
                   const int* __restrict__ row_start,
                   float* __restrict__ out,
                   int n_rows) {
    __shared__ int2 cvbuf[4][64];

    const int wave = __builtin_amdgcn_readfirstlane((int)(threadIdx.x >> 6));
    const int lane = threadIdx.x & 63;
    const int r    = blockIdx.x * 4 + wave;
    if (r >= n_rows) return;

    const int start   = row_start[r];
    const int end     = row_start[r + 1];
    const int quarter = lane >> 4;   // which nnz of the quad
    const int sub     = lane & 15;   // 16 lanes x 8 halves = 128 cols
    const char* __restrict__ whb = (const char*)wh;
    const int loff = sub << 4;       // sub*16 bytes
    int2* cv = cvbuf[wave];

    float4 accA = make_float4(0.f, 0.f, 0.f, 0.f);  // cols sub*8 + 0..3
    float4 accB = make_float4(0.f, 0.f, 0.f, 0.f);  // cols sub*8 + 4..7

    for (int base = start; base < end; base += 64) {
        const int navail = min(64, end - base);
        // stage (c, v): pad lanes get (valid col, v=0)
        const int idx = base + min(lane, navail - 1);
        int   c_l = cols[idx];
        float v_l = (lane < navail) ? vals[idx] : 0.f;
        cv[lane] = make_int2(c_l, __float_as_int(v_l));

        const int nquad  = (navail + 3) >> 2;
        const int nquad4 = (nquad + 3) & ~3;   // <= 16; pads have v=0

        for (int t = 0; t < nquad4; t += 4) {
            // ---- 4 broadcast LDS reads (independent, non-convergent) ----
            int2 p0 = cv[4 * (t + 0) + quarter];
            int2 p1 = cv[4 * (t + 1) + quarter];
            int2 p2 = cv[4 * (t + 2) + quarter];
            int2 p3 = cv[4 * (t + 3) + quarter];
            // ---- 4 independent 1KB gathers (each serves 4 nnz) ----
            uint4 q0 = *(const uint4*)(whb + (((size_t)(unsigned)p0.x) << 8) + loff);
            uint4 q1 = *(const uint4*)(whb + (((size_t)(unsigned)p1.x) << 8) + loff);
            uint4 q2 = *(const uint4*)(whb + (((size_t)(unsigned)p2.x) << 8) + loff);
            uint4 q3 = *(const uint4*)(whb + (((size_t)(unsigned)p3.x) << 8) + loff);
            // ---- consume in issue order ----
#pragma unroll
            for (int j = 0; j < 4; ++j) {
                uint4 q = (j == 0) ? q0 : (j == 1) ? q1 : (j == 2) ? q2 : q3;
                float v = __int_as_float(((j == 0) ? p0 : (j == 1) ? p1
                                        : (j == 2) ? p2 : p3).y);
                const __half2* h = (const __half2*)&q;
                float2 f0 = __half22float2(h[0]);
                float2 f1 = __half22float2(h[1]);
                float2 f2 = __half22float2(h[2]);
                float2 f3 = __half22float2(h[3]);
                accA.x = fmaf(v, f0.x, accA.x); accA.y = fmaf(v, f0.y, accA.y);
                accA.z = fmaf(v, f1.x, accA.z); accA.w = fmaf(v, f1.y, accA.w);
                accB.x = fmaf(v, f2.x, accB.x); accB.y = fmaf(v, f2.y, accB.y);
                accB.z = fmaf(v, f3.x, accB.z); accB.w = fmaf(v, f3.y, accB.w);
            }
        }
    }

    // fold the 4 quarters (disjoint nnz subsets)
#pragma unroll
    for (int d = 16; d <= 32; d <<= 1) {
        accA.x += __shfl_xor(accA.x, d); accA.y += __shfl_xor(accA.y, d);
        accA.z += __shfl_xor(accA.z, d); accA.w += __shfl_xor(accA.w, d);
        accB.x += __shfl_xor(accB.x, d); accB.y += __shfl_xor(accB.y, d);
        accB.z += __shfl_xor(accB.z, d); accB.w += __shfl_xor(accB.w, d);
    }

    if (quarter == 0) {
        float4* o = (float4*)(out + (size_t)r * OUT_UNITS + sub * 8);
        o[0] = accA;
        o[1] = accB;
    }
}

extern "C" void kernel_launch(void* const* d_in, const int* in_sizes, int n_in,
                              void* d_out, int out_size, void* d_ws, size_t ws_size,
                              hipStream_t stream) {
    const float* vals = (const float*)d_in[0];
    const float* w    = (const float*)d_in[1];
    const int*   rows = (const int*)d_in[2];
    const int*   cols = (const int*)d_in[3];
    float* out = (float*)d_out;

    const int nnz    = in_sizes[0];
    const int n_rows = out_size / OUT_UNITS;  // 16384
    const int w_n    = in_sizes[1];           // 8192*128 = 1048576

    // ws layout: [0, 64KB+4) row_start ; [128KB, 128KB+2MB) w fp16
    int*    row_start = (int*)d_ws;
    __half* wh        = (__half*)((char*)d_ws + (128 << 10));

    convert_w<<<(w_n / 4 + 255) / 256, 256, 0, stream>>>(
        (const float4*)w, (uint2*)wh, w_n / 4);
    build_row_starts<<<(nnz + 255) / 256, 256, 0, stream>>>(rows, row_start, nnz, n_rows);
    spmm_row_wave<<<(n_rows + 3) / 4, 256, 0, stream>>>(vals, wh, cols, row_start, out, n_rows);
}